// Round 12
// baseline (562.578 us; speedup 1.0000x reference)
//
#include <hip/hip_runtime.h>
#include <hip/hip_bf16.h>
#include <math.h>

#define B_SZ 128
#define N_OTH 2048
#define F_IMG 1024
#define F_TXT 512
#define D_EMB 512
#define TOT (B_SZ * N_OTH)

typedef __attribute__((ext_vector_type(8))) short short8;    // 8 bf16 (4 VGPR)
typedef __attribute__((ext_vector_type(16))) float f32x16;   // 32x32 MFMA acc

static __device__ __forceinline__ ushort f2bf(float f) {
    __hip_bfloat16 h = __float2bfloat16(f);   // HW RNE convert
    return *reinterpret_cast<ushort*>(&h);
}

// ---------------- fused: encoders (blocks 0..127) + W-prep (blocks 128..191) ----------------
__global__ __launch_bounds__(512) void k_prep(const float* __restrict__ in_img,
                                              const float* __restrict__ in_txt,
                                              const float* __restrict__ W_img,
                                              const float* __restrict__ W_txt,
                                              const float* __restrict__ p_ls,
                                              float* __restrict__ img,
                                              float* __restrict__ logit_in,
                                              ushort* __restrict__ wf) {
    if (blockIdx.x >= B_SZ) {
        // W_txt -> bf16 MFMA B-fragment repack:
        // frag = kstep(0..31)*16 + ct(0..15); lane l: col ct*32+(l&31), k = kstep*16+(l>>5)*8+j
        const int g = (blockIdx.x - B_SZ) * 512 + threadIdx.x;   // 32768 total
        const int l = g & 63;
        const int frag = g >> 6;
        const int kstep = frag >> 4;
        const int ct = frag & 15;
        const int col = ct * 32 + (l & 31);
        const int kb = kstep * 16 + (l >> 5) * 8;
        short8 o;
#pragma unroll
        for (int j = 0; j < 8; ++j) o[j] = (short)f2bf(W_txt[(kb + j) * D_EMB + col]);
        *(short8*)(wf + (size_t)g * 8) = o;
        return;
    }
    const int b = blockIdx.x;
    const int d = threadIdx.x;
    __shared__ float row[F_IMG];
    __shared__ float wsum[8];
    __shared__ float s_rn;
    const int lane = d & 63, wv = d >> 6;

    for (int i = d; i < F_IMG; i += 512) row[i] = in_img[b * F_IMG + i];
    __syncthreads();
    float acc = 0.f;
#pragma unroll 8
    for (int f = 0; f < F_IMG; ++f) acc = fmaf(row[f], W_img[f * D_EMB + d], acc);
    float sq = acc * acc;
#pragma unroll
    for (int off = 32; off > 0; off >>= 1) sq += __shfl_down(sq, off);
    if (lane == 0) wsum[wv] = sq;
    __syncthreads();
    if (d == 0) {
        float s = 0.f;
        for (int w = 0; w < 8; ++w) s += wsum[w];
        s_rn = 1.0f / sqrtf(s);
    }
    __syncthreads();
    const float iv = acc * s_rn;
    img[b * D_EMB + d] = iv;

    __syncthreads();
    row[d] = in_txt[b * F_TXT + d];
    __syncthreads();
    float tacc = 0.f;
#pragma unroll 8
    for (int f = 0; f < F_TXT; ++f) tacc = fmaf(row[f], W_txt[f * D_EMB + d], tacc);
    float tsq = tacc * tacc;
#pragma unroll
    for (int off = 32; off > 0; off >>= 1) tsq += __shfl_down(tsq, off);
    __syncthreads();
    if (lane == 0) wsum[wv] = tsq;
    __syncthreads();
    if (d == 0) {
        float s = 0.f;
        for (int w = 0; w < 8; ++w) s += wsum[w];
        s_rn = 1.0f / sqrtf(s);
    }
    __syncthreads();
    float pd = (tacc * s_rn) * iv;
#pragma unroll
    for (int off = 32; off > 0; off >>= 1) pd += __shfl_down(pd, off);
    __syncthreads();
    if (lane == 0) wsum[wv] = pd;
    __syncthreads();
    if (d == 0) {
        float s = 0.f;
        for (int w = 0; w < 8; ++w) s += wsum[w];
        logit_in[b] = expf(p_ls[0]) * s;
    }
}

// ---------------- persistent fused GEMM + num/den partial reduction ----------------
// Grid: 512 blocks (exactly 2/CU), 256 thr = 4 waves.
// Block p: h = p&1 (column half), pb = p>>1 owns strips [pb*16, pb*16+16).
// Per strip: 64 rows x 256 cols, BK=64, 8 K-tiles. Wave wv: cols [h*256+wv*64, +64),
// acc = 2m x 2n x f32x16 = 64. bf16 LDS A, 2 buffers, XOR swizzle, cvt once at stage.
// Steady-state pipeline runs 128 tiles/block; A-prefetch crosses strip boundaries;
// B addresses repeat each strip (L1/L2-warm). lgkm-only barriers.
__device__ __forceinline__ void loadA(const float* gs, float4 v[4]) {
    v[0] = *(const float4*)(gs + 0);
    v[1] = *(const float4*)(gs + 4);
    v[2] = *(const float4*)(gs + 8);
    v[3] = *(const float4*)(gs + 12);
}
__device__ __forceinline__ void loadB(short8 dst[4][2], const ushort* wbase, int t) {
#pragma unroll
    for (int ks = 0; ks < 4; ++ks)
#pragma unroll
        for (int n = 0; n < 2; ++n)
            dst[ks][n] = *(const short8*)(wbase + (size_t)((t * 4 + ks) * 16 + n) * 512);
}
__device__ __forceinline__ void cvtWrite(char* buf, int wb0, int wb1, const float4 v[4]) {
    short8 p0, p1;
    p0[0] = (short)f2bf(v[0].x); p0[1] = (short)f2bf(v[0].y); p0[2] = (short)f2bf(v[0].z); p0[3] = (short)f2bf(v[0].w);
    p0[4] = (short)f2bf(v[1].x); p0[5] = (short)f2bf(v[1].y); p0[6] = (short)f2bf(v[1].z); p0[7] = (short)f2bf(v[1].w);
    p1[0] = (short)f2bf(v[2].x); p1[1] = (short)f2bf(v[2].y); p1[2] = (short)f2bf(v[2].z); p1[3] = (short)f2bf(v[2].w);
    p1[4] = (short)f2bf(v[3].x); p1[5] = (short)f2bf(v[3].y); p1[6] = (short)f2bf(v[3].z); p1[7] = (short)f2bf(v[3].w);
    *(short8*)(buf + wb0) = p0;
    *(short8*)(buf + wb1) = p1;
}
__device__ __forceinline__ void tileMFMA(const ushort* sAt, const int rowbase[2], const int koff[4],
                                         const short8 bfr[4][2], f32x16 acc[2][2]) {
#pragma unroll
    for (int ks = 0; ks < 4; ++ks) {
        short8 af[2];
#pragma unroll
        for (int m = 0; m < 2; ++m)
            af[m] = *(const short8*)((const char*)sAt + rowbase[m] + koff[ks]);
#pragma unroll
        for (int m = 0; m < 2; ++m)
#pragma unroll
            for (int n = 0; n < 2; ++n)
                acc[m][n] = __builtin_amdgcn_mfma_f32_32x32x16_bf16(af[m], bfr[ks][n], acc[m][n], 0, 0, 0);
    }
}

__global__ __launch_bounds__(256, 2) void k_gemm(const float* __restrict__ oth,
                                                 const ushort* __restrict__ wf,
                                                 const float* __restrict__ img,
                                                 float* __restrict__ numA,    // [2][TOT]
                                                 float* __restrict__ denA) {  // [2][TOT]
    __shared__ ushort sA[2][64 * 64];   // 2 x 8 KB bf16, swizzled
    __shared__ float redN[4][64];
    __shared__ float redD[4][64];
    const int tid = threadIdx.x;
    const int l = tid & 63;
    const int wv = tid >> 6;
    const int p = blockIdx.x;              // 0..511
    const int h = p & 1;
    const int pb = p >> 1;                 // 0..255, owns strips pb*16..pb*16+15
    const int b = pb >> 1;                 // batch element (constant per block)

    // staging map: thread -> 1 row, 16 consecutive k (64 B global, 32 B LDS)
    const int srow = tid >> 2;             // 0..63
    const int sk0 = (tid & 3) * 16;
    const int swz = (srow & 7) << 4;
    const int wb0 = srow * 128 + ((sk0 * 2 + 0) ^ swz);
    const int wb1 = srow * 128 + ((sk0 * 2 + 16) ^ swz);

    // B fragments: ct = h*8 + wv*2 + n; frag = (t*4+ks)*16 + ct; addr = (frag*64+l)*8
    const ushort* wbase = wf + ((size_t)(h * 8 + wv * 2) * 64 + l) * 8;

    // A-read: row r = m*32 + (l&31); byte = r*128 + ((ks*32+(l>>5)*16) ^ ((l&7)<<4))
    int rowbase[2];
#pragma unroll
    for (int m = 0; m < 2; ++m) rowbase[m] = (m * 32 + (l & 31)) * 128;
    int koff[4];
#pragma unroll
    for (int ks = 0; ks < 4; ++ks) koff[ks] = ((ks * 32 + (l >> 5) * 16) ^ ((l & 7) << 4));

    // img columns (b constant per block)
    float ic[2];
#pragma unroll
    for (int n = 0; n < 2; ++n)
        ic[n] = img[b * D_EMB + h * 256 + wv * 64 + n * 32 + (l & 31)];

    float4 va[4], vb[4];
    short8 bfrA[4][2], bfrB[4][2];

#pragma unroll 1
    for (int s = 0; s < 16; ++s) {
        const size_t row0 = ((size_t)pb * 16 + s) * 64;
        const float* gsrcs = oth + (row0 + srow) * F_TXT + sk0;        // this strip
        const float* gsrcn = oth + (row0 + 64 + srow) * F_TXT + sk0;   // next strip

        if (s == 0) {
            // prologue (once per block): A(0)->va, A(1)->vb, B(0)->bfrA; stage A(0)
            loadA(gsrcs + 0 * 64, va);
            loadA(gsrcs + 1 * 64, vb);
            loadB(bfrA, wbase, 0);
            __builtin_amdgcn_sched_barrier(0);
            cvtWrite((char*)sA[0], wb0, wb1, va);
            asm volatile("s_waitcnt lgkmcnt(0)" ::: "memory");
            __builtin_amdgcn_sched_barrier(0);
            __builtin_amdgcn_s_barrier();
            __builtin_amdgcn_sched_barrier(0);
        }

        f32x16 acc[2][2];
#pragma unroll
        for (int m = 0; m < 2; ++m)
#pragma unroll
            for (int n = 0; n < 2; ++n)
#pragma unroll
                for (int r = 0; r < 16; ++r) acc[m][n][r] = 0.f;

#pragma unroll
        for (int t = 0; t < 8; ++t) {
            const bool lastTile = (s == 15) && (t == 7);
            // S1: issue B for next tile index ((t+1)&7) — same addrs every strip (cache-warm)
            if (!lastTile) {
                if ((t & 1) == 0) loadB(bfrB, wbase, (t + 1) & 7);
                else              loadB(bfrA, wbase, (t + 1) & 7);
            }
            __builtin_amdgcn_sched_barrier(0);
            // S2: issue A two tiles ahead (crosses strip boundary at t>=6)
            if (!((s == 15) && (t >= 6))) {
                const float* g2 = (t < 6) ? (gsrcs + (t + 2) * 64) : (gsrcn + (t - 6) * 64);
                if ((t & 1) == 0) loadA(g2, va);
                else              loadA(g2, vb);
            }
            __builtin_amdgcn_sched_barrier(0);
            // S3: MFMA tile t (LDS buf t&1 + resident B regs)
            if ((t & 1) == 0) tileMFMA(sA[0], rowbase, koff, bfrA, acc);
            else              tileMFMA(sA[1], rowbase, koff, bfrB, acc);
            // S4: cvt + stage A(next tile) into the other LDS buffer
            if (!lastTile) {
                if ((t & 1) == 0) cvtWrite((char*)sA[1], wb0, wb1, vb);
                else              cvtWrite((char*)sA[0], wb0, wb1, va);
            }
            // S5: lgkm-only barrier; in-flight global loads cross it
            __builtin_amdgcn_sched_barrier(0);
            asm volatile("s_waitcnt lgkmcnt(0)" ::: "memory");
            __builtin_amdgcn_s_barrier();
            __builtin_amdgcn_sched_barrier(0);
        }

        // per-strip epilogue: partial num/den for this column half
#pragma unroll
        for (int m = 0; m < 2; ++m) {
#pragma unroll
            for (int rg = 0; rg < 16; ++rg) {
                const float pv = acc[m][0][rg];
                const float qv = acc[m][1][rg];
                float tn = pv * ic[0] + qv * ic[1];
                float td = pv * pv + qv * qv;
#pragma unroll
                for (int off = 1; off <= 16; off <<= 1) {
                    tn += __shfl_xor(tn, off);
                    td += __shfl_xor(td, off);
                }
                if ((l & 31) == 0) {
                    const int r = m * 32 + (rg & 3) + 8 * (rg >> 2) + 4 * (l >> 5);
                    redN[wv][r] = tn;
                    redD[wv][r] = td;
                }
            }
        }
        __syncthreads();
        if (tid < 64) {
            float tn = 0.f, td = 0.f;
#pragma unroll
            for (int w = 0; w < 4; ++w) { tn += redN[w][tid]; td += redD[w][tid]; }
            numA[(size_t)h * TOT + row0 + tid] = tn;
            denA[(size_t)h * TOT + row0 + tid] = td;
        }
    }
}

// ---------------- logits + full bitonic sort + output assembly ----------------
__global__ __launch_bounds__(512) void k_topk(const float* __restrict__ numA,
                                              const float* __restrict__ denA,
                                              const float* __restrict__ logit_in,
                                              const float* __restrict__ p_ls,
                                              float* __restrict__ out) {
    const int b = blockIdx.x;
    const int tid = threadIdx.x;
    const float scale = expf(p_ls[0]);
    __shared__ float a[N_OTH];
    for (int i = tid; i < N_OTH; i += 512) {
        const size_t idx = (size_t)b * N_OTH + i;
        const float nu = numA[idx] + numA[TOT + idx];
        const float de = denA[idx] + denA[TOT + idx];
        a[i] = scale * nu / sqrtf(de);
    }
    __syncthreads();
    for (unsigned k = 2; k <= N_OTH; k <<= 1) {
        for (unsigned j = k >> 1; j > 0; j >>= 1) {
#pragma unroll
            for (int s = 0; s < N_OTH / 512; ++s) {
                const unsigned i = tid + s * 512u;
                const unsigned ixj = i ^ j;
                if (ixj > i) {
                    const bool asc = ((i & k) == 0);
                    const float x = a[i], y = a[ixj];
                    if ((x > y) == asc) { a[i] = y; a[ixj] = x; }
                }
            }
            __syncthreads();
        }
    }
    if (tid < 128) {
        const int j = tid;
        float v;
        if (j == b) {
            v = logit_in[b];
        } else {
            const int m = j - (j > b ? 1 : 0);
            v = a[N_OTH - 1 - m];
        }
        out[b * 128 + j] = v;
    }
}

extern "C" void kernel_launch(void* const* d_in, const int* in_sizes, int n_in,
                              void* d_out, int out_size, void* d_ws, size_t ws_size,
                              hipStream_t stream) {
    const float* in_img = (const float*)d_in[0];
    const float* in_txt = (const float*)d_in[1];
    const float* oth    = (const float*)d_in[2];
    const float* W_img  = (const float*)d_in[3];
    const float* W_txt  = (const float*)d_in[4];
    const float* p_ls   = (const float*)d_in[5];
    float* out = (float*)d_out;

    float* ws = (float*)d_ws;
    float* img      = ws;                                   // 65536
    float* logit_in = ws + 65536;                           // 128
    float* numA     = ws + 65536 + 128;                     // 2*TOT
    float* denA     = numA + 2 * TOT;                       // 2*TOT
    ushort* wfrag   = (ushort*)(denA + 2 * TOT);            // 262144 ushorts

    k_prep<<<B_SZ + 64, 512, 0, stream>>>(in_img, in_txt, W_img, W_txt, p_ls, img, logit_in, wfrag);
    k_gemm<<<512, 256, 0, stream>>>(oth, wfrag, img, numA, denA);
    k_topk<<<B_SZ, 512, 0, stream>>>(numA, denA, logit_in, p_ls, out);
}

// Round 13
// 413.951 us; speedup vs baseline: 1.3590x; 1.3590x over previous
//
#include <hip/hip_runtime.h>
#include <hip/hip_bf16.h>
#include <math.h>

#define B_SZ 128
#define N_OTH 2048
#define F_IMG 1024
#define F_TXT 512
#define D_EMB 512
#define TOT (B_SZ * N_OTH)

typedef __attribute__((ext_vector_type(8))) short short8;   // 8 bf16 (4 VGPR)
typedef __attribute__((ext_vector_type(4))) float f32x4;    // 16x16 MFMA acc

static __device__ __forceinline__ ushort f2bf(float f) {
    __hip_bfloat16 h = __float2bfloat16(f);   // HW RNE convert
    return *reinterpret_cast<ushort*>(&h);
}

// ---------------- fused: encoders (blocks 0..127) + W-prep (blocks 128..191) ----------------
__global__ __launch_bounds__(512) void k_prep(const float* __restrict__ in_img,
                                              const float* __restrict__ in_txt,
                                              const float* __restrict__ W_img,
                                              const float* __restrict__ W_txt,
                                              const float* __restrict__ p_ls,
                                              float* __restrict__ img,
                                              float* __restrict__ logit_in,
                                              ushort* __restrict__ wf) {
    if (blockIdx.x >= B_SZ) {
        // W_txt -> bf16 16x16x32-MFMA B-fragment repack:
        // frag = kk(0..15)*32 + ct(0..31); lane l: col = ct*16+(l&15), k = kk*32+(l>>4)*8+j
        const int g = (blockIdx.x - B_SZ) * 512 + threadIdx.x;   // 32768 total
        const int l = g & 63;
        const int frag = g >> 6;
        const int kk = frag >> 5;
        const int ct = frag & 31;
        const int col = ct * 16 + (l & 15);
        const int kb = kk * 32 + (l >> 4) * 8;
        short8 o;
#pragma unroll
        for (int j = 0; j < 8; ++j) o[j] = (short)f2bf(W_txt[(kb + j) * D_EMB + col]);
        *(short8*)(wf + (size_t)g * 8) = o;
        return;
    }
    const int b = blockIdx.x;
    const int d = threadIdx.x;
    __shared__ float row[F_IMG];
    __shared__ float wsum[8];
    __shared__ float s_rn;
    const int lane = d & 63, wv = d >> 6;

    for (int i = d; i < F_IMG; i += 512) row[i] = in_img[b * F_IMG + i];
    __syncthreads();
    float acc = 0.f;
#pragma unroll 8
    for (int f = 0; f < F_IMG; ++f) acc = fmaf(row[f], W_img[f * D_EMB + d], acc);
    float sq = acc * acc;
#pragma unroll
    for (int off = 32; off > 0; off >>= 1) sq += __shfl_down(sq, off);
    if (lane == 0) wsum[wv] = sq;
    __syncthreads();
    if (d == 0) {
        float s = 0.f;
        for (int w = 0; w < 8; ++w) s += wsum[w];
        s_rn = 1.0f / sqrtf(s);
    }
    __syncthreads();
    const float iv = acc * s_rn;
    img[b * D_EMB + d] = iv;

    __syncthreads();
    row[d] = in_txt[b * F_TXT + d];
    __syncthreads();
    float tacc = 0.f;
#pragma unroll 8
    for (int f = 0; f < F_TXT; ++f) tacc = fmaf(row[f], W_txt[f * D_EMB + d], tacc);
    float tsq = tacc * tacc;
#pragma unroll
    for (int off = 32; off > 0; off >>= 1) tsq += __shfl_down(tsq, off);
    __syncthreads();
    if (lane == 0) wsum[wv] = tsq;
    __syncthreads();
    if (d == 0) {
        float s = 0.f;
        for (int w = 0; w < 8; ++w) s += wsum[w];
        s_rn = 1.0f / sqrtf(s);
    }
    __syncthreads();
    float pd = (tacc * s_rn) * iv;
#pragma unroll
    for (int off = 32; off > 0; off >>= 1) pd += __shfl_down(pd, off);
    __syncthreads();
    if (lane == 0) wsum[wv] = pd;
    __syncthreads();
    if (d == 0) {
        float s = 0.f;
        for (int w = 0; w < 8; ++w) s += wsum[w];
        logit_in[b] = expf(p_ls[0]) * s;
    }
}

// ---------------- fused GEMM + num/den (atomic partial) ----------------
// Grid: 4096 strips x 4 col-quarters = 16384 blocks; consecutive blockIdx = the 4
// quarters of one strip (co-dispatched across XCDs -> L3 shares the A-tile).
// Block: 256 thr = 4 waves, BM=64 rows x BN=128 cols, BK=64, K=512 (8 tiles).
// Wave wv: 64 rows x cols [h*128 + wv*32, +32). acc = 4m x 2n x f32x4 = 32 VGPR.
// Small state (~100 VGPR, 18 KB LDS) -> 4-5 independent blocks/CU (16-20 waves):
// latency hiding via TLP, not choreography. Tile order (R7-proven):
//   B(t) -> A(t+1) -> MFMA(t) -> cvt+write(t+1) -> __syncthreads.
__device__ __forceinline__ void loadA(const float* gs, float4 v[4]) {
    v[0] = *(const float4*)(gs + 0);
    v[1] = *(const float4*)(gs + 4);
    v[2] = *(const float4*)(gs + 8);
    v[3] = *(const float4*)(gs + 12);
}
__device__ __forceinline__ void cvtWrite(char* buf, int wb0, int wb1, const float4 v[4]) {
    short8 p0, p1;
    p0[0] = (short)f2bf(v[0].x); p0[1] = (short)f2bf(v[0].y); p0[2] = (short)f2bf(v[0].z); p0[3] = (short)f2bf(v[0].w);
    p0[4] = (short)f2bf(v[1].x); p0[5] = (short)f2bf(v[1].y); p0[6] = (short)f2bf(v[1].z); p0[7] = (short)f2bf(v[1].w);
    p1[0] = (short)f2bf(v[2].x); p1[1] = (short)f2bf(v[2].y); p1[2] = (short)f2bf(v[2].z); p1[3] = (short)f2bf(v[2].w);
    p1[4] = (short)f2bf(v[3].x); p1[5] = (short)f2bf(v[3].y); p1[6] = (short)f2bf(v[3].z); p1[7] = (short)f2bf(v[3].w);
    *(short8*)(buf + wb0) = p0;
    *(short8*)(buf + wb1) = p1;
}

__global__ __launch_bounds__(256, 4) void k_gemm(const float* __restrict__ oth,
                                                 const ushort* __restrict__ wf,
                                                 const float* __restrict__ img,
                                                 float* __restrict__ numA,    // [TOT], pre-zeroed
                                                 float* __restrict__ denA) {  // [TOT], pre-zeroed
    __shared__ ushort sA[2][64 * 64];   // 2 x 8 KB bf16, swizzled
    __shared__ float redN[4][64];
    __shared__ float redD[4][64];
    const int tid = threadIdx.x;
    const int l = tid & 63;
    const int wv = tid >> 6;
    const int strip = blockIdx.x >> 2;     // 0..4095
    const int h = blockIdx.x & 3;          // column quarter
    const int b = strip >> 5;              // batch element
    const size_t row0 = (size_t)strip * 64;

    // staging map: thread -> 1 row, 16 consecutive k (64 B global, 32 B LDS)
    const int srow = tid >> 2;             // 0..63
    const int sk0 = (tid & 3) * 16;
    const float* gsrc = oth + (row0 + srow) * F_TXT + sk0;
    const int swz = (srow & 7) << 4;
    const int wb0 = srow * 128 + ((sk0 * 2 + 0) ^ swz);
    const int wb1 = srow * 128 + ((sk0 * 2 + 16) ^ swz);

    // B fragments: ct = h*8 + wv*2 + n; frag = kk*32 + ct; addr = (frag*64+l)*8 ushorts
    const ushort* wbase = wf + ((size_t)(h * 8 + wv * 2) * 64 + l) * 8;

    // A-read: row r = m*16 + (l&15); byte = r*128 + ((kkl*64 + (l>>4)*16) ^ ((l&7)<<4))
    int rowbase[4];
#pragma unroll
    for (int m = 0; m < 4; ++m) rowbase[m] = (m * 16 + (l & 15)) * 128;
    int koff[2];
#pragma unroll
    for (int kkl = 0; kkl < 2; ++kkl)
        koff[kkl] = ((kkl * 64 + (l >> 4) * 16) ^ ((l & 7) << 4));

    f32x4 acc[4][2];
#pragma unroll
    for (int m = 0; m < 4; ++m)
#pragma unroll
        for (int n = 0; n < 2; ++n)
            acc[m][n] = (f32x4){0.f, 0.f, 0.f, 0.f};

    float4 va[4];
    short8 bfr[2][2];

    // prologue: A(0) staged; B(0) issued after A(0) (A consumed first -> clean drains)
    loadA(gsrc, va);
#pragma unroll
    for (int kkl = 0; kkl < 2; ++kkl)
#pragma unroll
        for (int n = 0; n < 2; ++n)
            bfr[kkl][n] = *(const short8*)(wbase + (size_t)(kkl * 16384 + n * 512));
    cvtWrite((char*)sA[0], wb0, wb1, va);
    __syncthreads();

#pragma unroll
    for (int t = 0; t < 8; ++t) {
        const int cur = t & 1;
        // A-prefetch t+1 (HBM/L3); issued after B(t) -> waiting on B never drains it
        if (t < 7) loadA(gsrc + (t + 1) * 64, va);
        __builtin_amdgcn_sched_barrier(0);
        // MFMA tile t (2 k-steps of 32)
#pragma unroll
        for (int kkl = 0; kkl < 2; ++kkl) {
            short8 af[4];
#pragma unroll
            for (int m = 0; m < 4; ++m)
                af[m] = *(const short8*)((const char*)sA[cur] + rowbase[m] + koff[kkl]);
#pragma unroll
            for (int m = 0; m < 4; ++m)
#pragma unroll
                for (int n = 0; n < 2; ++n)
                    acc[m][n] = __builtin_amdgcn_mfma_f32_16x16x32_bf16(af[m], bfr[kkl][n], acc[m][n], 0, 0, 0);
        }
        __builtin_amdgcn_sched_barrier(0);
        if (t < 7) {
            // B(t+1) issue (L2-warm); then cvt+stage A(t+1) (its wait leaves B in flight)
#pragma unroll
            for (int kkl = 0; kkl < 2; ++kkl)
#pragma unroll
                for (int n = 0; n < 2; ++n)
                    bfr[kkl][n] = *(const short8*)(wbase + (size_t)(((t + 1) * 2 + kkl) * 16384 + n * 512));
            __builtin_amdgcn_sched_barrier(0);
            cvtWrite((char*)sA[cur ^ 1], wb0, wb1, va);
        }
        __syncthreads();
    }

    // epilogue: C col = l&15 (global h*128 + wv*32 + n*16 + (l&15)); row = m*16 + (l>>4)*4 + rg
    float ic[2];
#pragma unroll
    for (int n = 0; n < 2; ++n)
        ic[n] = img[b * D_EMB + h * 128 + wv * 32 + n * 16 + (l & 15)];
#pragma unroll
    for (int m = 0; m < 4; ++m) {
#pragma unroll
        for (int rg = 0; rg < 4; ++rg) {
            const float pv = acc[m][0][rg];
            const float qv = acc[m][1][rg];
            float tn = pv * ic[0] + qv * ic[1];
            float td = pv * pv + qv * qv;
#pragma unroll
            for (int off = 1; off <= 8; off <<= 1) {
                tn += __shfl_xor(tn, off);
                td += __shfl_xor(td, off);
            }
            if ((l & 15) == 0) {
                const int r = m * 16 + (l >> 4) * 4 + rg;
                redN[wv][r] = tn;
                redD[wv][r] = td;
            }
        }
    }
    __syncthreads();
    if (tid < 64) {
        float tn = 0.f, td = 0.f;
#pragma unroll
        for (int w = 0; w < 4; ++w) { tn += redN[w][tid]; td += redD[w][tid]; }
        atomicAdd(&numA[row0 + tid], tn);
        atomicAdd(&denA[row0 + tid], td);
    }
}

// ---------------- logits + full bitonic sort + output assembly ----------------
__global__ __launch_bounds__(512) void k_topk(const float* __restrict__ numA,
                                              const float* __restrict__ denA,
                                              const float* __restrict__ logit_in,
                                              const float* __restrict__ p_ls,
                                              float* __restrict__ out) {
    const int b = blockIdx.x;
    const int tid = threadIdx.x;
    const float scale = expf(p_ls[0]);
    __shared__ float a[N_OTH];
    for (int i = tid; i < N_OTH; i += 512) {
        const size_t idx = (size_t)b * N_OTH + i;
        a[i] = scale * numA[idx] / sqrtf(denA[idx]);
    }
    __syncthreads();
    for (unsigned k = 2; k <= N_OTH; k <<= 1) {
        for (unsigned j = k >> 1; j > 0; j >>= 1) {
#pragma unroll
            for (int s = 0; s < N_OTH / 512; ++s) {
                const unsigned i = tid + s * 512u;
                const unsigned ixj = i ^ j;
                if (ixj > i) {
                    const bool asc = ((i & k) == 0);
                    const float x = a[i], y = a[ixj];
                    if ((x > y) == asc) { a[i] = y; a[ixj] = x; }
                }
            }
            __syncthreads();
        }
    }
    if (tid < 128) {
        const int j = tid;
        float v;
        if (j == b) {
            v = logit_in[b];
        } else {
            const int m = j - (j > b ? 1 : 0);
            v = a[N_OTH - 1 - m];
        }
        out[b * 128 + j] = v;
    }
}

extern "C" void kernel_launch(void* const* d_in, const int* in_sizes, int n_in,
                              void* d_out, int out_size, void* d_ws, size_t ws_size,
                              hipStream_t stream) {
    const float* in_img = (const float*)d_in[0];
    const float* in_txt = (const float*)d_in[1];
    const float* oth    = (const float*)d_in[2];
    const float* W_img  = (const float*)d_in[3];
    const float* W_txt  = (const float*)d_in[4];
    const float* p_ls   = (const float*)d_in[5];
    float* out = (float*)d_out;

    float* ws = (float*)d_ws;
    float* img      = ws;                                   // 65536
    float* logit_in = ws + 65536;                           // 128
    float* numA     = ws + 65536 + 128;                     // TOT
    float* denA     = numA + TOT;                           // TOT
    ushort* wfrag   = (ushort*)(denA + TOT);                // 262144 ushorts

    hipMemsetAsync(numA, 0, (size_t)2 * TOT * sizeof(float), stream);
    k_prep<<<B_SZ + 64, 512, 0, stream>>>(in_img, in_txt, W_img, W_txt, p_ls, img, logit_in, wfrag);
    k_gemm<<<(TOT / 64) * 4, 256, 0, stream>>>(oth, wfrag, img, numA, denA);
    k_topk<<<B_SZ, 512, 0, stream>>>(numA, denA, logit_in, p_ls, out);
}